// Round 9
// baseline (507.312 us; speedup 1.0000x reference)
//
#include <hip/hip_runtime.h>
#include <math.h>

#define L2C   65536
#define NC    (2 * L2C)
#define FINC  8
#define FOUTC 8
#define KC    13
#define BLOCK 256
#define EWB   (FOUTC * FINC * KC * 4)  // 3328 B per edge (int32-mask mode)
#define EBB   (FOUTC * FINC * KC)      // 832 B per edge (bool-mask mode)
#define GRID  2048                     // 8 blocks/CU, 32 waves/CU = device capacity
#define GRIDH (GRID / 2)               // 1024 blocks per branch
#define EPW   16                       // 1024 blk * 4 waves * 16 = 65536 edges/branch

constexpr double E_D = 2.71828182845904523536;
constexpr float SCALE_F = (float)((2.0 + 2.0 * E_D) / (E_D - 1.0));
typedef unsigned int u32;
typedef u32 u32x4 __attribute__((ext_vector_type(4)));   // clang vector: legal
typedef u32 u32x2 __attribute__((ext_vector_type(2)));   // for nontemporal builtins

// d_ws: xt = x transposed to (N, FIN), 4 MiB at offset 0.
__global__ __launch_bounds__(256)
void transpose_x_kernel(const float* __restrict__ x, float* __restrict__ xt) {
    int n = blockIdx.x * 256 + threadIdx.x;
    float v[FINC];
#pragma unroll
    for (int i = 0; i < FINC; ++i) v[i] = x[(size_t)i * NC + n];
    float4* dst = reinterpret_cast<float4*>(xt + ((size_t)n << 3));
    dst[0] = make_float4(v[0], v[1], v[2], v[3]);
    dst[1] = make_float4(v[4], v[5], v[6], v[7]);
}

// R16 = R15 with the compile fix: __builtin_nontemporal_load needs a clang
// ext_vector_type, not HIP's uint4 class. Structure/theory unchanged:
//
// R15: NT A/B (R7) proved the ~3 TB/s pin was cache-path allocation, not a
// fabric cap (harness memset hits 6.7 TB/s). Remaining gap = LDS staging
// discipline: 6 blocks/CU (occ 55%) + a vmcnt(0) barrier per 13 KB tile.
// Fix: drop LDS entirely. Lane's 13 mask words are contiguous at lane*13
// (layout [e][o][i][k]) -> load 4 ALIGNED dwordx4 (64 B) per lane covering
// words [(lane*13)&~3, +16), pack 16 nonzero flags into a u32, shift by
// lane&3 -> 13-bit mask. No barriers, no cross-lane ops. 2048 persistent
// blocks (32 waves/CU, all resident), 16 edges/wave, software-pipelined:
// issue e+1's NT loads -> compute e -> pack flags (wait lands after a full
// compute phase). Raw regs transient (16) -> no R5-style spill at the
// 64-VGPR cap. Tripwire: WRITE_SIZE >> 8 MB next profile = spill, revert cap.
__global__ __launch_bounds__(BLOCK, 8)
void edge_conv_kernel(const float* __restrict__ xt,
                      const float* __restrict__ Wh, const float* __restrict__ Wv,
                      const float* __restrict__ bh, const float* __restrict__ bv,
                      const unsigned char* __restrict__ mh,
                      const unsigned char* __restrict__ mv,
                      const int* __restrict__ kh, const int* __restrict__ kv,
                      float* __restrict__ out)
{
    const int tid  = threadIdx.x;
    const int lane = tid & 63;
    const int wave = tid >> 6;
    const int o    = lane >> 3;
    const int i    = lane & 7;

    const int  b     = blockIdx.x;
    const bool hor   = (b < GRIDH);
    const int  bb    = hor ? b : b - GRIDH;
    const int  cbase = hor ? 0 : L2C;

    const float*         W    = hor ? Wh : Wv;
    const float*         bias = hor ? bh : bv;
    const unsigned char* mask = hor ? mh : mv;
    const int*           ker  = hor ? kh : kv;

    // Mask-encoding probe (proven): int32/float32 0/1 masks have byte
    // offset%4==1 always zero; 1-byte bools are random. Grid-uniform.
    const unsigned char probe = mh[(size_t)(lane * 4 + 1)];
    const bool words = (__ballot(probe != 0) == 0ull);

    // Per-lane weight row + bias (cached, reused 16x per wave).
    float wreg[KC];
#pragma unroll
    for (int k = 0; k < KC; ++k) wreg[k] = W[lane * KC + k];
    const float biaso = bias[o];

    const int e0 = (bb * 4 + wave) * EPW;   // this wave's 16 consecutive edges

    if (words) {
        const int vb  = (lane * 52) & ~15;  // aligned 64 B window in edge
        const int off = lane & 3;           // word offset of lane*13 within it
        u32x4 r0, r1, r2, r3;
        auto issue = [&](int e) {
            const u32x4* p = reinterpret_cast<const u32x4*>(
                mask + (size_t)e * EWB + vb);          // 16B-aligned
            r0 = __builtin_nontemporal_load(p + 0);
            r1 = __builtin_nontemporal_load(p + 1);
            r2 = __builtin_nontemporal_load(p + 2);
            r3 = __builtin_nontemporal_load(p + 3);
        };
        auto pack = [&]() -> u32 {
            u32 f = 0;
            f |= (u32)(r0[0] != 0u) << 0;  f |= (u32)(r0[1] != 0u) << 1;
            f |= (u32)(r0[2] != 0u) << 2;  f |= (u32)(r0[3] != 0u) << 3;
            f |= (u32)(r1[0] != 0u) << 4;  f |= (u32)(r1[1] != 0u) << 5;
            f |= (u32)(r1[2] != 0u) << 6;  f |= (u32)(r1[3] != 0u) << 7;
            f |= (u32)(r2[0] != 0u) << 8;  f |= (u32)(r2[1] != 0u) << 9;
            f |= (u32)(r2[2] != 0u) << 10; f |= (u32)(r2[3] != 0u) << 11;
            f |= (u32)(r3[0] != 0u) << 12; f |= (u32)(r3[1] != 0u) << 13;
            f |= (u32)(r3[2] != 0u) << 14; f |= (u32)(r3[3] != 0u) << 15;
            return (f >> off) & 0x1FFFu;
        };

        issue(e0);
        u32 mb = pack();
        for (int j = 0; j < EPW; ++j) {
            const int e = e0 + j;
            if (j + 1 < EPW) issue(e + 1);      // NT loads land under compute

            const int  eu = __builtin_amdgcn_readfirstlane(e);
            const int* kc = ker + (size_t)eu * KC;   // uniform -> s_loads
            float acc0 = 0.0f, acc1 = 0.0f;
#pragma unroll
            for (int k = 0; k < KC; ++k) {
                const float xv = (xt + ((size_t)kc[k] << 3))[i];  // 32 B seg, L2-hot
                const float wm = ((mb >> k) & 1u) ? wreg[k] : 0.0f;
                if (k & 1) acc1 = fmaf(wm, xv, acc1);
                else       acc0 = fmaf(wm, xv, acc0);
            }
            float acc = acc0 + acc1;
            acc += __shfl_xor(acc, 1);
            acc += __shfl_xor(acc, 2);
            acc += __shfl_xor(acc, 4);
            if (i == 0) {
                const float z   = acc + biaso;
                const float sig = 1.0f / (1.0f + __expf(-z));
                out[(size_t)o * NC + (cbase + e)] = (sig - 0.5f) * SCALE_F;
            }
            if (j + 1 < EPW) mb = pack();       // waits raws: full compute elapsed
        }
    } else {
        // bool bytes: lane's 13 bytes at lane*13; aligned 32 B window
        // (clamped so lane 63 stays inside the 832 B edge).
        const int lb  = lane * KC;
        const int vb  = (lb & ~15) > (EBB - 32) ? (EBB - 32) : (lb & ~15);
        const int off = lb - vb;                 // 0..19; off+12 <= 31
        u32x4 r0, r1;
        auto issueB = [&](int e) {
            const u32x4* p = reinterpret_cast<const u32x4*>(
                mask + (size_t)e * EBB + vb);
            r0 = __builtin_nontemporal_load(p + 0);
            r1 = __builtin_nontemporal_load(p + 1);
        };
        auto packB = [&]() -> u32 {
            u32 f = 0;
            const u32 d[8] = {r0[0], r0[1], r0[2], r0[3], r1[0], r1[1], r1[2], r1[3]};
#pragma unroll
            for (int q = 0; q < 8; ++q) {
                f |= (u32)((d[q] & 0x000000FFu) != 0u) << (4 * q + 0);
                f |= (u32)((d[q] & 0x0000FF00u) != 0u) << (4 * q + 1);
                f |= (u32)((d[q] & 0x00FF0000u) != 0u) << (4 * q + 2);
                f |= (u32)((d[q] & 0xFF000000u) != 0u) << (4 * q + 3);
            }
            return (f >> off) & 0x1FFFu;
        };

        issueB(e0);
        u32 mb = packB();
        for (int j = 0; j < EPW; ++j) {
            const int e = e0 + j;
            if (j + 1 < EPW) issueB(e + 1);

            const int  eu = __builtin_amdgcn_readfirstlane(e);
            const int* kc = ker + (size_t)eu * KC;
            float acc0 = 0.0f, acc1 = 0.0f;
#pragma unroll
            for (int k = 0; k < KC; ++k) {
                const float xv = (xt + ((size_t)kc[k] << 3))[i];
                const float wm = ((mb >> k) & 1u) ? wreg[k] : 0.0f;
                if (k & 1) acc1 = fmaf(wm, xv, acc1);
                else       acc0 = fmaf(wm, xv, acc0);
            }
            float acc = acc0 + acc1;
            acc += __shfl_xor(acc, 1);
            acc += __shfl_xor(acc, 2);
            acc += __shfl_xor(acc, 4);
            if (i == 0) {
                const float z   = acc + biaso;
                const float sig = 1.0f / (1.0f + __expf(-z));
                out[(size_t)o * NC + (cbase + e)] = (sig - 0.5f) * SCALE_F;
            }
            if (j + 1 < EPW) mb = packB();
        }
    }
}

extern "C" void kernel_launch(void* const* d_in, const int* in_sizes, int n_in,
                              void* d_out, int out_size, void* d_ws, size_t ws_size,
                              hipStream_t stream) {
    const float*         x   = (const float*)d_in[0];
    const float*         Wh  = (const float*)d_in[1];
    const float*         Wv  = (const float*)d_in[2];
    const float*         bh  = (const float*)d_in[3];
    const float*         bv  = (const float*)d_in[4];
    const unsigned char* mh  = (const unsigned char*)d_in[5];
    const unsigned char* mv  = (const unsigned char*)d_in[6];
    const int*           kh  = (const int*)d_in[7];
    const int*           kv  = (const int*)d_in[8];
    float* out = (float*)d_out;
    float* xt  = (float*)d_ws;

    transpose_x_kernel<<<NC / 256, 256, 0, stream>>>(x, xt);
    edge_conv_kernel<<<GRID, BLOCK, 0, stream>>>(
        xt, Wh, Wv, bh, bv, mh, mv, kh, kv, out);
}

// Round 10
// 442.297 us; speedup vs baseline: 1.1470x; 1.1470x over previous
//
#include <hip/hip_runtime.h>
#include <math.h>

#define L2C   65536
#define NC    (2 * L2C)
#define FINC  8
#define FOUTC 8
#define KC    13
#define BLOCK 256
#define EPB   4
#define EWORDS (FOUTC * FINC * KC)     // 832 mask elements per edge
#define TILE_WORDS (EPB * EWORDS)      // 3328 dwords per tile (int32-mask mode)
#define TILE_WBYTES (TILE_WORDS * 4)   // 13312 B
#define TILE_BBYTES (EPB * EWORDS)     // 3328 B (bool-mask mode)
#define GRID  1536                     // 6 blocks/CU (LDS-limited) -> ALL resident
#define GRIDH (GRID / 2)               // 768 blocks per branch
#define TPBR  (L2C / EPB)              // 16384 tiles per branch

constexpr double E_D = 2.71828182845904523536;
constexpr float SCALE_F = (float)((2.0 + 2.0 * E_D) / (E_D - 1.0));

typedef unsigned int u32;
typedef __attribute__((address_space(1))) const u32 gu32;
typedef __attribute__((address_space(3))) u32 lu32;

// Direct global->LDS DMA, 16 B per lane. LDS dest = wave-uniform base +
// lane*16 (hardware-defined); our staging layout is exactly linear.
//
// R17: aux 0x2 (NT) -> 0x12 (NT | SC1). R7's NT A/B gave edge ~127 us, but
// FETCH stayed 298 MB < 436 MB logical and HBM-read rate has NEVER exceeded
// ~2.1 TB/s in any round — the stream still flows through the L3 fill path
// (NT bit only affects L2 eviction priority). SC1 raises the op to system
// scope: hypothesis is it bypasses the L3 allocation/fill choke entirely.
// Single-variable A/B vs R7: if L3-fill was the choke, FETCH -> ~440 MB and
// edge dur -> ~90-105 us; if HBM-read caps at ~2.1 TB/s, dur worsens (we
// lose L3's assist) -> revert to aux=2 and treat R7 as structure-bound.
__device__ __forceinline__ void gll16(const void* g, u32* l) {
    __builtin_amdgcn_global_load_lds((gu32*)g, (lu32*)l, 16, 0, /*NT|SC1*/0x12);
}

// d_ws: xt = x transposed to (N, FIN), 4 MiB at offset 0.
__global__ __launch_bounds__(256)
void transpose_x_kernel(const float* __restrict__ x, float* __restrict__ xt) {
    int n = blockIdx.x * 256 + threadIdx.x;
    float v[FINC];
#pragma unroll
    for (int i = 0; i < FINC; ++i) v[i] = x[(size_t)i * NC + n];
    float4* dst = reinterpret_cast<float4*>(xt + ((size_t)n << 3));
    dst[0] = make_float4(v[0], v[1], v[2], v[3]);
    dst[1] = make_float4(v[4], v[5], v[6], v[7]);
}

// Structure identical to R6/R7 (persistent blocks, gll double-buffer, one
// barrier per tile, lane-local mask rows in LDS). R9's no-LDS variant taught:
// per-instruction load density matters — 52 B-stride windows cost 4x
// transaction amplification (1.81 TB/s); dense gll staging is the right form.
__global__ __launch_bounds__(BLOCK, 6)
void edge_conv_kernel(const float* __restrict__ xt,
                      const float* __restrict__ Wh, const float* __restrict__ Wv,
                      const float* __restrict__ bh, const float* __restrict__ bv,
                      const unsigned char* __restrict__ mh,
                      const unsigned char* __restrict__ mv,
                      const int* __restrict__ kh, const int* __restrict__ kv,
                      float* __restrict__ out)
{
    __shared__ __align__(16) u32 msh[2][TILE_WORDS];   // 2 x 13312 B

    const int tid  = threadIdx.x;
    const int lane = tid & 63;
    const int wave = tid >> 6;
    const int o    = lane >> 3;
    const int i    = lane & 7;

    const int  b     = blockIdx.x;
    const bool hor   = (b < GRIDH);
    const int  bb    = hor ? b : b - GRIDH;
    const int  cbase = hor ? 0 : L2C;

    const float*         W    = hor ? Wh : Wv;
    const float*         bias = hor ? bh : bv;
    const unsigned char* mask = hor ? mh : mv;
    const int*           ker  = hor ? kh : kv;

    // Mask-encoding probe (proven): int32/float32 0/1 masks have byte
    // offset%4==1 always zero; 1-byte bools are random. Grid-uniform.
    const unsigned char probe = mh[(size_t)(lane * 4 + 1)];
    const bool words = (__ballot(probe != 0) == 0ull);

    // Per-lane weight row + bias, loaded once (cached, reused 21x).
    float wreg[KC];
#pragma unroll
    for (int k = 0; k < KC; ++k) wreg[k] = W[lane * KC + k];
    const float biaso = bias[o];

    // Stage one tile into msh[buf] via global_load_lds (NT|SC1).
    // words: 832 uint4 = 13 chunks of 64; wave handles c = wave, wave+4,
    //        wave+8; wave 0 also c=12. LDS base uniform per instr; HW adds
    //        lane*16 -> linear, matching the flat tile layout.
    // bytes: 208 uint4 = chunks 0..2 (waves 0-2) + 16 uint4 (wave 3, lane<16).
    auto stage = [&](int buf, int t) {
        if (words) {
            const char* g = (const char*)mask + (size_t)t * TILE_WBYTES;
#pragma unroll
            for (int j = 0; j < 3; ++j) {
                const int c = wave + 4 * j;
                gll16(g + (size_t)(c * 64 + lane) * 16, &msh[buf][c * 256]);
            }
            if (wave == 0)
                gll16(g + (size_t)(12 * 64 + lane) * 16, &msh[buf][12 * 256]);
        } else {
            const char* g = (const char*)mask + (size_t)t * TILE_BBYTES;
            if (wave < 3)
                gll16(g + (size_t)(wave * 64 + lane) * 16, &msh[buf][wave * 256]);
            else if (lane < 16)
                gll16(g + (size_t)(3 * 64 + lane) * 16, &msh[buf][3 * 256]);
        }
    };

    int t = bb;
    stage(0, t);
    __syncthreads();                       // drains prologue glls (vmcnt 0)

    int buf = 0;
    for (; t < TPBR; t += GRIDH, buf ^= 1) {
        const int tn = t + GRIDH;
        if (tn < TPBR) stage(buf ^ 1, tn); // issue-early: lands under compute

        const int be  = t * EPB + wave;
        const int bes = __builtin_amdgcn_readfirstlane(be);  // force SMEM ker loads

        int cols[KC];
#pragma unroll
        for (int k = 0; k < KC; ++k) cols[k] = ker[(size_t)bes * KC + k];

        float acc0 = 0.0f, acc1 = 0.0f;
        if (words) {
            const u32* mrow = &msh[buf][wave * EWORDS + lane * KC];
#pragma unroll
            for (int k = 0; k < KC; ++k) {
                const float xv = xt[((size_t)cols[k] << 3) + i]; // 32 B seg / wave / k
                const float wm = mrow[k] ? wreg[k] : 0.0f;
                if (k & 1) acc1 = fmaf(wm, xv, acc1);
                else       acc0 = fmaf(wm, xv, acc0);
            }
        } else {
            const unsigned char* mrow = (const unsigned char*)&msh[buf][0]
                                        + wave * EWORDS + lane * KC;
#pragma unroll
            for (int k = 0; k < KC; ++k) {
                const float xv = xt[((size_t)cols[k] << 3) + i];
                const float wm = mrow[k] ? wreg[k] : 0.0f;
                if (k & 1) acc1 = fmaf(wm, xv, acc1);
                else       acc0 = fmaf(wm, xv, acc0);
            }
        }
        float acc = acc0 + acc1;
        acc += __shfl_xor(acc, 1);
        acc += __shfl_xor(acc, 2);
        acc += __shfl_xor(acc, 4);
        const float z = acc + biaso;

        __syncthreads();   // all waves done reading msh[buf]; glls for tn drained

        if (i == 0) {      // store after the barrier: keeps it out of the drain
            const float sig = 1.0f / (1.0f + __expf(-z));
            out[(size_t)o * NC + (cbase + be)] = (sig - 0.5f) * SCALE_F;
        }
    }
}

extern "C" void kernel_launch(void* const* d_in, const int* in_sizes, int n_in,
                              void* d_out, int out_size, void* d_ws, size_t ws_size,
                              hipStream_t stream) {
    const float*         x   = (const float*)d_in[0];
    const float*         Wh  = (const float*)d_in[1];
    const float*         Wv  = (const float*)d_in[2];
    const float*         bh  = (const float*)d_in[3];
    const float*         bv  = (const float*)d_in[4];
    const unsigned char* mh  = (const unsigned char*)d_in[5];
    const unsigned char* mv  = (const unsigned char*)d_in[6];
    const int*           kh  = (const int*)d_in[7];
    const int*           kv  = (const int*)d_in[8];
    float* out = (float*)d_out;
    float* xt  = (float*)d_ws;

    transpose_x_kernel<<<NC / 256, 256, 0, stream>>>(x, xt);
    edge_conv_kernel<<<GRID, BLOCK, 0, stream>>>(
        xt, Wh, Wv, bh, bv, mh, mv, kh, kv, out);
}